// Round 1
// baseline (641.606 us; speedup 1.0000x reference)
//
#include <hip/hip_runtime.h>

// ActorCritic fused kernel R4: LSTM scan (B=1024,T=256,F=128,H=128) + MLP heads.
//
// R3 was serial-latency-bound (MfmaUtil 6.7%, VALUBusy 13%, Occupancy 6%):
// 64 blocks use 64/256 CUs and each step's ~3900-cycle critical path is
// exec-masked activation VALU + 8-deep MFMA chains + barrier turnaround.
// Duration = 256 x per-step latency of ONE block, so the only lever is the
// per-block step. R4:
//  - grid 64 -> 256 blocks (4 batch rows each): per-block activation work /4,
//    all CUs busy. (MFMA count/block unchanged: M=16 is the minimum tile.)
//  - z redistribution via wave-local LDS (4x ds_write_b128 from q==0 lanes,
//    1x ds_read_b128 per lane, 80B stride = conflict-free): activation runs
//    1 element/lane instead of exec-masked 4 elements in 16/64 lanes.
//  - dual accumulators: z_t is completed with the h-part MFMAs only (kt 4..7,
//    4-deep chain) on top of the x-projection carried from last step; the
//    x-projection of t+1 (kt 0..3) issues into a fresh accumulator and fills
//    the activation latency shadow. Same FP accumulation order as R3.
//  - still exactly 1 barrier per step (double-buffered A in fragment order).

typedef _Float16 f16x8 __attribute__((ext_vector_type(8)));
typedef _Float16 f16x4 __attribute__((ext_vector_type(4)));
typedef float    f32x4 __attribute__((ext_vector_type(4)));

#define NLOG2E (-1.4426950408889634f)

__device__ __forceinline__ float rcpf(float x) { return __builtin_amdgcn_rcpf(x); }
__device__ __forceinline__ float ex2(float x)  { return __builtin_amdgcn_exp2f(x); }

__global__ __launch_bounds__(512, 2)
void ac_fused(const float* __restrict__ hin,
              const float* __restrict__ Wx, const float* __restrict__ Wh,
              const float* __restrict__ bh,
              const float* __restrict__ Wa1, const float* __restrict__ ba1,
              const float* __restrict__ Wa2, const float* __restrict__ ba2,
              const float* __restrict__ Wa3, const float* __restrict__ ba3,
              const float* __restrict__ logstd,
              const float* __restrict__ Wc1, const float* __restrict__ bc1,
              const float* __restrict__ Wc2, const float* __restrict__ bc2,
              const float* __restrict__ Wc3, const float* __restrict__ bc3,
              float* __restrict__ out)
{
    constexpr int T = 256, F = 128, H = 128, G = 512; // G = 4*H
    constexpr int R = 4;                              // batch rows per block

    // A staging in MFMA fragment order: chunk = kt*64 + quad*16 + m holds
    // A[m][k], k = kt*32 + quad*8 + j. Rows m >= R stay zero forever.
    __shared__ f16x8 Abuf[2][512];          // 2 x 8 KB
    __shared__ float zbuf[8 * 320];         // per-wave z redistribution (80B stride)
    __shared__ float xf[R][F + 1];          // final hidden (fp32)
    __shared__ float hb[2][R][257];         // head layer ping-pong

    const int tid  = threadIdx.x;
    const int lane = tid & 63;
    const int wv   = tid >> 6;    // wave 0..7
    const int m16  = lane & 15;
    const int q    = lane >> 4;   // quad 0..3
    const int r0   = blockIdx.x << 2;

    // ---- load weight B-fragments into registers ----
    // wave wv covers column (s*128 + wv*16 + m16) in each gate section s
    f16x8 bw[4][8];
    const int ncol = (wv << 4) + m16;
    #pragma unroll
    for (int kt = 0; kt < 8; ++kt) {
        #pragma unroll
        for (int s = 0; s < 4; ++s) {
            f16x8 v;
            #pragma unroll
            for (int j = 0; j < 8; ++j) {
                const int k = (kt << 5) + (q << 3) + j;   // 0..255
                const float w = (k < F) ? Wx[k * G + s * H + ncol]
                                        : Wh[(k - F) * G + s * H + ncol];
                v[j] = (_Float16)w;
            }
            bw[s][kt] = v;
        }
    }
    // bias folded into the exp2 argument:  sig(z+b) = rcp(1 + 2^(z*NLOG2E + nb))
    const float nbi = NLOG2E * bh[0 * H + ncol];
    const float nbf = NLOG2E * bh[1 * H + ncol];
    const float nbg = 2.0f * NLOG2E * bh[2 * H + ncol];
    const float nbo = NLOG2E * bh[3 * H + ncol];

    // ---- x staging: thread stages half-chunk (chunk = tid>>1, half = tid&1),
    //      only chunks whose row m < R are live ----
    const int xc = tid >> 1;              // chunk 0..255 (x half of K)
    const int xh = tid & 1;               // which f16x4 inside the chunk
    const int xm = xc & 15;               // batch row within tile
    const bool xact = (xm < R);
    const int xk0 = ((xc >> 6) << 5) + (((xc >> 4) & 3) << 3) + (xh << 2); // k 0..124
    const float* pxbase = hin + (size_t)(r0 + (xact ? xm : 0)) * T * F + xk0;

    // ---- zero both A buffers (rows >= R must read as 0), then stage x0/x1 ----
    {
        f16x8 zz = {};
        ((f16x8*)Abuf)[tid]       = zz;
        ((f16x8*)Abuf)[tid + 512] = zz;
    }
    __syncthreads();
    if (xact) {
        const float4 x0 = *(const float4*)(pxbase);
        const float4 x1 = *(const float4*)(pxbase + F);
        f16x4 p0, p1;
        p0[0] = (_Float16)x0.x; p0[1] = (_Float16)x0.y;
        p0[2] = (_Float16)x0.z; p0[3] = (_Float16)x0.w;
        p1[0] = (_Float16)x1.x; p1[1] = (_Float16)x1.y;
        p1[2] = (_Float16)x1.z; p1[3] = (_Float16)x1.w;
        *(f16x4*)((_Float16*)&Abuf[0][0] + xc * 8 + xh * 4) = p0;
        *(f16x4*)((_Float16*)&Abuf[1][0] + xc * 8 + xh * 4) = p1;
    }
    __syncthreads();

    // ---- prologue: zc = P_0 = x_0 @ Wx  (x-part, kt 0..3) ----
    f32x4 zc0 = {0.f,0.f,0.f,0.f}, zc1 = {0.f,0.f,0.f,0.f};
    f32x4 zc2 = {0.f,0.f,0.f,0.f}, zc3 = {0.f,0.f,0.f,0.f};
    #pragma unroll
    for (int kt = 0; kt < 4; ++kt) {
        const f16x8 af = Abuf[0][(kt << 6) + lane];
        zc0 = __builtin_amdgcn_mfma_f32_16x16x32_f16(af, bw[0][kt], zc0, 0, 0, 0);
        zc1 = __builtin_amdgcn_mfma_f32_16x16x32_f16(af, bw[1][kt], zc1, 0, 0, 0);
        zc2 = __builtin_amdgcn_mfma_f32_16x16x32_f16(af, bw[2][kt], zc2, 0, 0, 0);
        zc3 = __builtin_amdgcn_mfma_f32_16x16x32_f16(af, bw[3][kt], zc3, 0, 0, 0);
    }

    // z redistribution addresses (floats). Write (q==0 lanes): m16*20 + r*4.
    // Read (all lanes): element (row = q, dim = ncol) at m16*20 + q*4.
    const int zbase = wv * 320 + m16 * 20;
    const int zrd   = zbase + (q << 2);
    // h-write position in the next A buffer: k = F + ncol, row = q.
    const int kk    = F + ncol;
    const int whalf = ((((kk >> 5) << 6) + (((kk >> 3) & 3) << 4) + q) << 3) + (kk & 7);

    float cstate = 0.0f;   // cell state for this lane's (row q, dim ncol)
    float hcur   = 0.0f;
    f32x4 zn0, zn1, zn2, zn3;

    auto STEP = [&](f32x4& a0, f32x4& a1, f32x4& a2, f32x4& a3,
                    f32x4& b0, f32x4& b1, f32x4& b2, f32x4& b3,
                    const int cur, const int t) {
        const f16x8* Ac = &Abuf[cur][0];
        const f16x8* An = &Abuf[cur ^ 1][0];

        // prefetch x_{t+2} from global (hidden under MFMA + activation)
        float4 xn = {0.f, 0.f, 0.f, 0.f};
        if (xact) {
            const int tp = (t + 2 < T) ? t + 2 : T - 1;
            xn = *(const float4*)(pxbase + (size_t)tp * F);
        }

        // complete z_t: h-part MFMAs (kt 4..7) on top of carried x-projection
        #pragma unroll
        for (int kt = 4; kt < 8; ++kt) {
            const f16x8 af = Ac[(kt << 6) + lane];
            a0 = __builtin_amdgcn_mfma_f32_16x16x32_f16(af, bw[0][kt], a0, 0, 0, 0);
            a1 = __builtin_amdgcn_mfma_f32_16x16x32_f16(af, bw[1][kt], a1, 0, 0, 0);
            a2 = __builtin_amdgcn_mfma_f32_16x16x32_f16(af, bw[2][kt], a2, 0, 0, 0);
            a3 = __builtin_amdgcn_mfma_f32_16x16x32_f16(af, bw[3][kt], a3, 0, 0, 0);
        }
        // start z_{t+1}: x-part MFMAs (kt 0..3) -- independent, fills the shadow
        b0 = f32x4{0.f,0.f,0.f,0.f}; b1 = f32x4{0.f,0.f,0.f,0.f};
        b2 = f32x4{0.f,0.f,0.f,0.f}; b3 = f32x4{0.f,0.f,0.f,0.f};
        #pragma unroll
        for (int kt = 0; kt < 4; ++kt) {
            const f16x8 af = An[(kt << 6) + lane];
            b0 = __builtin_amdgcn_mfma_f32_16x16x32_f16(af, bw[0][kt], b0, 0, 0, 0);
            b1 = __builtin_amdgcn_mfma_f32_16x16x32_f16(af, bw[1][kt], b1, 0, 0, 0);
            b2 = __builtin_amdgcn_mfma_f32_16x16x32_f16(af, bw[2][kt], b2, 0, 0, 0);
            b3 = __builtin_amdgcn_mfma_f32_16x16x32_f16(af, bw[3][kt], b3, 0, 0, 0);
        }

        // redistribute z_t so every lane owns one (row, dim) element.
        // Wave-local LDS, DS ops are in-order per wave: no barrier needed.
        if (q == 0) {
            #pragma unroll
            for (int r = 0; r < 4; ++r) {
                f32x4 v = { a0[r], a1[r], a2[r], a3[r] };
                *(f32x4*)&zbuf[zbase + (r << 2)] = v;
            }
        }
        const f32x4 zz = *(const f32x4*)&zbuf[zrd];   // {i,f,g,o} pre-activation

        // cell update (scalar per lane)
        const float iv = rcpf(1.0f + ex2(fmaf(zz[0], NLOG2E, nbi)));
        const float fv = rcpf(1.0f + ex2(fmaf(zz[1], NLOG2E, nbf)));
        const float gv = 2.0f * rcpf(1.0f + ex2(fmaf(zz[2], 2.0f * NLOG2E, nbg))) - 1.0f;
        const float ov = rcpf(1.0f + ex2(fmaf(zz[3], NLOG2E, nbo)));
        cstate = fv * cstate + iv * gv;
        const float th = 2.0f * rcpf(1.0f + ex2(cstate * (2.0f * NLOG2E))) - 1.0f;
        hcur = ov * th;

        // h_t -> next buffer h-region (read next step as kt 4..7 fragments)
        ((_Float16*)An)[whalf] = (_Float16)hcur;

        // x_{t+2} -> current buffer x-region (read next step as kt 0..3)
        if (xact) {
            f16x4 pk;
            pk[0] = (_Float16)xn.x; pk[1] = (_Float16)xn.y;
            pk[2] = (_Float16)xn.z; pk[3] = (_Float16)xn.w;
            *(f16x4*)((_Float16*)Ac + xc * 8 + xh * 4) = pk;
        }
        __syncthreads();
    };

    for (int t = 0; t < T; t += 2) {
        STEP(zc0, zc1, zc2, zc3, zn0, zn1, zn2, zn3, 0, t);
        STEP(zn0, zn1, zn2, zn3, zc0, zc1, zc2, zc3, 1, t + 1);
    }

    // ---- final hidden (fp32, pre-rounding) to LDS for the heads ----
    xf[q][ncol] = hcur;
    __syncthreads();

    // ---- MLP heads (fp32 VALU; tiny FLOPs) ----
    const int n  = tid & 255;
    const int rh = tid >> 8;   // 0..1 -> rows {2*rh, 2*rh+1}

    auto tanhl = [&](float x) { return 2.0f * rcpf(1.0f + ex2(x * (2.0f * NLOG2E))) - 1.0f; };

    auto layer = [&](const float* __restrict__ W, const float* __restrict__ bv,
                     const float* xin, int xs, int K, float* yout, int ys) {
        float acc0, acc1;
        const float b = bv[n];
        acc0 = b; acc1 = b;
        #pragma unroll 4
        for (int k = 0; k < K; ++k) {
            const float w = W[k * 256 + n];
            acc0 += xin[(rh * 2 + 0) * xs + k] * w;
            acc1 += xin[(rh * 2 + 1) * xs + k] * w;
        }
        yout[(rh * 2 + 0) * ys + n] = tanhl(acc0);
        yout[(rh * 2 + 1) * ys + n] = tanhl(acc1);
    };

    layer(Wa1, ba1, &xf[0][0], F + 1, 128, &hb[0][0][0], 257);   // actor L1
    __syncthreads();
    layer(Wa2, ba2, &hb[0][0][0], 257, 256, &hb[1][0][0], 257);  // actor L2
    __syncthreads();
    layer(Wc1, bc1, &xf[0][0], F + 1, 128, &hb[0][0][0], 257);   // critic L1
    if (tid < 32) {                                              // actor L3: mean + std
        const int r = tid >> 3, aa = tid & 7;
        float acc = ba3[aa];
        #pragma unroll 4
        for (int k = 0; k < 256; ++k) acc += hb[1][r][k] * Wa3[k * 8 + aa];
        out[(size_t)(r0 + r) * 17 + aa]     = acc;
        out[(size_t)(r0 + r) * 17 + 8 + aa] = __expf(logstd[aa]);
    }
    __syncthreads();
    layer(Wc2, bc2, &hb[0][0][0], 257, 256, &hb[1][0][0], 257);  // critic L2
    __syncthreads();
    if (tid < 4) {                                               // critic L3: value
        const int r = tid;
        float acc = bc3[0];
        #pragma unroll 4
        for (int k = 0; k < 256; ++k) acc += hb[1][r][k] * Wc3[k];
        out[(size_t)(r0 + r) * 17 + 16] = acc;
    }
}

extern "C" void kernel_launch(void* const* d_in, const int* in_sizes, int n_in,
                              void* d_out, int out_size, void* d_ws, size_t ws_size,
                              hipStream_t stream) {
    (void)in_sizes; (void)n_in; (void)d_ws; (void)ws_size; (void)out_size;
    const float* hin = (const float*)d_in[0];
    const float* Wx  = (const float*)d_in[1];
    const float* Wh  = (const float*)d_in[2];
    const float* bh  = (const float*)d_in[3];
    const float* Wa1 = (const float*)d_in[4];
    const float* ba1 = (const float*)d_in[5];
    const float* Wa2 = (const float*)d_in[6];
    const float* ba2 = (const float*)d_in[7];
    const float* Wa3 = (const float*)d_in[8];
    const float* ba3 = (const float*)d_in[9];
    const float* ls  = (const float*)d_in[10];
    const float* Wc1 = (const float*)d_in[11];
    const float* bc1 = (const float*)d_in[12];
    const float* Wc2 = (const float*)d_in[13];
    const float* bc2 = (const float*)d_in[14];
    const float* Wc3 = (const float*)d_in[15];
    const float* bc3 = (const float*)d_in[16];

    hipLaunchKernelGGL(ac_fused, dim3(256), dim3(512), 0, stream,
                       hin, Wx, Wh, bh, Wa1, ba1, Wa2, ba2, Wa3, ba3, ls,
                       Wc1, bc1, Wc2, bc2, Wc3, bc3, (float*)d_out);
}

// Round 2
// 503.506 us; speedup vs baseline: 1.2743x; 1.2743x over previous
//
#include <hip/hip_runtime.h>

// ActorCritic fused kernel R5: LSTM scan (B=1024,T=256,F=128,H=128) + MLP heads.
//
// R4 post-mortem: WRITE_SIZE 23.6MB = scratch spill (reg budget 256/wave at
// 2 waves/SIMD exceeded); per-step critical path still held a full HBM load
// because __syncthreads drains vmcnt(0) at every barrier; zbuf transpose
// added ~150cy LDS latency + bank conflicts. Occupancy is register-capped at
// 2 waves/SIMD, so grid stays 256 (1 block/CU) and we shorten the step:
//  - ROW REPLICATION: A rows m hold batch row m&3. D rows 4q+g = batch row g,
//    so every lane holds all 4 rows' z in regs g=0..3; lane (q,m16) selects
//    row q with 3 cndmask (static idx). No LDS z-transpose at all.
//  - RAW BARRIERS (T4): s_waitcnt lgkmcnt(0) + s_barrier keeps global loads
//    in flight across barriers. 2-deep x prefetch: load x_{t+4} at step t,
//    store x_{t+2} (loaded 2 barriers ago) -> HBM latency off the step path.
//  - h written to 4 replicated A positions (4x ds_write_b16, hidden).
//  - dual accumulators kept: h-part (kt4..7) completes z_t, x-part (kt0..3)
//    of t+1 issues into the other set and covers activation latency.

typedef _Float16 f16x8 __attribute__((ext_vector_type(8)));
typedef _Float16 f16x4 __attribute__((ext_vector_type(4)));
typedef float    f32x4 __attribute__((ext_vector_type(4)));

#define NLOG2E (-1.4426950408889634f)

__device__ __forceinline__ float rcpf(float x) { return __builtin_amdgcn_rcpf(x); }
__device__ __forceinline__ float ex2(float x)  { return __builtin_amdgcn_exp2f(x); }

__global__ __launch_bounds__(512, 2)
void ac_fused(const float* __restrict__ hin,
              const float* __restrict__ Wx, const float* __restrict__ Wh,
              const float* __restrict__ bh,
              const float* __restrict__ Wa1, const float* __restrict__ ba1,
              const float* __restrict__ Wa2, const float* __restrict__ ba2,
              const float* __restrict__ Wa3, const float* __restrict__ ba3,
              const float* __restrict__ logstd,
              const float* __restrict__ Wc1, const float* __restrict__ bc1,
              const float* __restrict__ Wc2, const float* __restrict__ bc2,
              const float* __restrict__ Wc3, const float* __restrict__ bc3,
              float* __restrict__ out)
{
    constexpr int T = 256, F = 128, H = 128, G = 512; // G = 4*H
    constexpr int R = 4;                              // batch rows per block

    // A staging in MFMA fragment order: chunk = kt*64 + quad*16 + m holds
    // A[m][k], k = kt*32 + quad*8 + j. Row m carries batch row (m & 3).
    __shared__ f16x8 Abuf[2][512];          // 2 x 8 KB
    __shared__ float xf[R][F + 1];          // final hidden (fp32)
    __shared__ float hb[2][R][257];         // head layer ping-pong

    const int tid  = threadIdx.x;
    const int lane = tid & 63;
    const int wv   = tid >> 6;    // wave 0..7
    const int m16  = lane & 15;
    const int q    = lane >> 4;   // quad 0..3
    const int r0   = blockIdx.x << 2;

    // ---- load weight B-fragments into registers ----
    // wave wv covers column (s*128 + wv*16 + m16) in each gate section s
    f16x8 bw[4][8];
    const int ncol = (wv << 4) + m16;
    #pragma unroll
    for (int kt = 0; kt < 8; ++kt) {
        #pragma unroll
        for (int s = 0; s < 4; ++s) {
            f16x8 v;
            #pragma unroll
            for (int j = 0; j < 8; ++j) {
                const int k = (kt << 5) + (q << 3) + j;   // 0..255
                const float w = (k < F) ? Wx[k * G + s * H + ncol]
                                        : Wh[(k - F) * G + s * H + ncol];
                v[j] = (_Float16)w;
            }
            bw[s][kt] = v;
        }
    }
    // bias folded into the exp2 argument:  sig(z+b) = rcp(1 + 2^(z*NLOG2E + nb))
    const float nbi = NLOG2E * bh[0 * H + ncol];
    const float nbf = NLOG2E * bh[1 * H + ncol];
    const float nbg = 2.0f * NLOG2E * bh[2 * H + ncol];
    const float nbo = NLOG2E * bh[3 * H + ncol];

    // ---- x staging: thread stages half-chunk (chunk = tid>>1, half = tid&1).
    //      All threads active: chunk row m = xc&15 carries batch row xc&3. ----
    const int xc    = tid >> 1;             // chunk 0..255 (x half of K)
    const int xhalf = tid & 1;              // which f16x4 inside the chunk
    const int xrow  = xc & 3;               // batch row within tile
    const int xk0   = ((xc >> 6) << 5) + (((xc >> 4) & 3) << 3) + (xhalf << 2);
    const float* pxbase = hin + (size_t)(r0 + xrow) * T * F + xk0;

    // h-write base: k = F + ncol; replicated rows m = q, q+4, q+8, q+12.
    const int kk        = F + ncol;
    const int chunkbase = ((kk >> 5) << 6) + (((kk >> 3) & 3) << 4);
    const int whalf0    = ((chunkbase + q) << 3) + (kk & 7);

    // ---- prologue staging: x0 -> buf0, x1 -> buf1 (replicated), h regions 0 ----
    {
        const float4 x0 = *(const float4*)(pxbase);
        const float4 x1 = *(const float4*)(pxbase + F);
        f16x4 p0, p1;
        p0[0] = (_Float16)x0.x; p0[1] = (_Float16)x0.y;
        p0[2] = (_Float16)x0.z; p0[3] = (_Float16)x0.w;
        p1[0] = (_Float16)x1.x; p1[1] = (_Float16)x1.y;
        p1[2] = (_Float16)x1.z; p1[3] = (_Float16)x1.w;
        *(f16x4*)((_Float16*)&Abuf[0][0] + xc * 8 + xhalf * 4) = p0;
        *(f16x4*)((_Float16*)&Abuf[1][0] + xc * 8 + xhalf * 4) = p1;
        if (tid < 256) {
            f16x8 zz = {};
            Abuf[0][256 + tid] = zz;   // h region (kt 4..7) = h_{-1} = 0
            Abuf[1][256 + tid] = zz;
        }
    }
    __syncthreads();

    // ---- pipeline loads: x2 (store at step 0), x3 (store at step 1) ----
    float4 xA = *(const float4*)(pxbase + 2 * (size_t)F);
    float4 xB = *(const float4*)(pxbase + 3 * (size_t)F);

    // ---- prologue: zc = x_0 @ Wx  (x-part, kt 0..3 of buf0) ----
    f32x4 zc0 = {0.f,0.f,0.f,0.f}, zc1 = {0.f,0.f,0.f,0.f};
    f32x4 zc2 = {0.f,0.f,0.f,0.f}, zc3 = {0.f,0.f,0.f,0.f};
    #pragma unroll
    for (int kt = 0; kt < 4; ++kt) {
        const f16x8 af = Abuf[0][(kt << 6) + lane];
        zc0 = __builtin_amdgcn_mfma_f32_16x16x32_f16(af, bw[0][kt], zc0, 0, 0, 0);
        zc1 = __builtin_amdgcn_mfma_f32_16x16x32_f16(af, bw[1][kt], zc1, 0, 0, 0);
        zc2 = __builtin_amdgcn_mfma_f32_16x16x32_f16(af, bw[2][kt], zc2, 0, 0, 0);
        zc3 = __builtin_amdgcn_mfma_f32_16x16x32_f16(af, bw[3][kt], zc3, 0, 0, 0);
    }
    // protect buf0 x-region (still being read above by other waves) from
    // step 0's x-store: full barrier before entering the loop.
    __syncthreads();

    float cstate = 0.0f;   // cell state for this lane's (row q, dim ncol)
    float hcur   = 0.0f;
    f32x4 zn0, zn1, zn2, zn3;
    const bool qlo = (q & 1) != 0;
    const bool qhi = (q & 2) != 0;

    auto STEP = [&](f32x4& a0, f32x4& a1, f32x4& a2, f32x4& a3,
                    f32x4& b0, f32x4& b1, f32x4& b2, f32x4& b3,
                    const int cur, const int t) {
        const f16x8* Ac = &Abuf[cur][0];
        const f16x8* An = &Abuf[cur ^ 1][0];

        // issue x_{t+4} (stays in flight across 2 raw barriers; stored t+2 from now)
        const int tp = (t + 4 < T) ? t + 4 : T - 1;
        const float4 xn = *(const float4*)(pxbase + (size_t)tp * F);

        // complete z_t: h-part MFMAs (kt 4..7) on top of carried x-projection
        #pragma unroll
        for (int kt = 4; kt < 8; ++kt) {
            const f16x8 af = Ac[(kt << 6) + lane];
            a0 = __builtin_amdgcn_mfma_f32_16x16x32_f16(af, bw[0][kt], a0, 0, 0, 0);
            a1 = __builtin_amdgcn_mfma_f32_16x16x32_f16(af, bw[1][kt], a1, 0, 0, 0);
            a2 = __builtin_amdgcn_mfma_f32_16x16x32_f16(af, bw[2][kt], a2, 0, 0, 0);
            a3 = __builtin_amdgcn_mfma_f32_16x16x32_f16(af, bw[3][kt], a3, 0, 0, 0);
        }
        // start z_{t+1}: x-part MFMAs (kt 0..3) -- independent, fills the shadow
        b0 = f32x4{0.f,0.f,0.f,0.f}; b1 = f32x4{0.f,0.f,0.f,0.f};
        b2 = f32x4{0.f,0.f,0.f,0.f}; b3 = f32x4{0.f,0.f,0.f,0.f};
        #pragma unroll
        for (int kt = 0; kt < 4; ++kt) {
            const f16x8 af = An[(kt << 6) + lane];
            b0 = __builtin_amdgcn_mfma_f32_16x16x32_f16(af, bw[0][kt], b0, 0, 0, 0);
            b1 = __builtin_amdgcn_mfma_f32_16x16x32_f16(af, bw[1][kt], b1, 0, 0, 0);
            b2 = __builtin_amdgcn_mfma_f32_16x16x32_f16(af, bw[2][kt], b2, 0, 0, 0);
            b3 = __builtin_amdgcn_mfma_f32_16x16x32_f16(af, bw[3][kt], b3, 0, 0, 0);
        }

        // every lane holds all 4 rows' z in regs g=0..3 (row replication);
        // select row q with static-index cndmask chains.
        const float zi = qhi ? (qlo ? a0[3] : a0[2]) : (qlo ? a0[1] : a0[0]);
        const float zf = qhi ? (qlo ? a1[3] : a1[2]) : (qlo ? a1[1] : a1[0]);
        const float zg = qhi ? (qlo ? a2[3] : a2[2]) : (qlo ? a2[1] : a2[0]);
        const float zo = qhi ? (qlo ? a3[3] : a3[2]) : (qlo ? a3[1] : a3[0]);

        const float iv = rcpf(1.0f + ex2(fmaf(zi, NLOG2E, nbi)));
        const float fv = rcpf(1.0f + ex2(fmaf(zf, NLOG2E, nbf)));
        const float gv = 2.0f * rcpf(1.0f + ex2(fmaf(zg, 2.0f * NLOG2E, nbg))) - 1.0f;
        const float ov = rcpf(1.0f + ex2(fmaf(zo, NLOG2E, nbo)));
        cstate = fv * cstate + iv * gv;
        const float th = 2.0f * rcpf(1.0f + ex2(cstate * (2.0f * NLOG2E))) - 1.0f;
        hcur = ov * th;

        // h_t -> next buffer h-region, 4 replicated rows (m = q + 4u)
        {
            const _Float16 hh = (_Float16)hcur;
            _Float16* hp = (_Float16*)An + whalf0;
            hp[0]  = hh;
            hp[32] = hh;
            hp[64] = hh;
            hp[96] = hh;
        }

        // x_{t+2} (loaded 2 steps ago) -> current buffer x-region
        {
            f16x4 pk;
            pk[0] = (_Float16)xA.x; pk[1] = (_Float16)xA.y;
            pk[2] = (_Float16)xA.z; pk[3] = (_Float16)xA.w;
            *(f16x4*)((_Float16*)Ac + xc * 8 + xhalf * 4) = pk;
        }
        xA = xB; xB = xn;

        // raw barrier: drain LDS (cross-wave visibility) but leave the global
        // x loads in flight (counted vmcnt wait happens at their use).
        asm volatile("s_waitcnt lgkmcnt(0)" ::: "memory");
        __builtin_amdgcn_s_barrier();
    };

    for (int t = 0; t < T; t += 2) {
        STEP(zc0, zc1, zc2, zc3, zn0, zn1, zn2, zn3, 0, t);
        STEP(zn0, zn1, zn2, zn3, zc0, zc1, zc2, zc3, 1, t + 1);
    }

    // ---- final hidden (fp32, pre-rounding) to LDS for the heads ----
    xf[q][ncol] = hcur;
    __syncthreads();

    // ---- MLP heads (fp32 VALU; tiny FLOPs) ----
    const int n  = tid & 255;
    const int rh = tid >> 8;   // 0..1 -> rows {2*rh, 2*rh+1}

    auto tanhl = [&](float x) { return 2.0f * rcpf(1.0f + ex2(x * (2.0f * NLOG2E))) - 1.0f; };

    auto layer = [&](const float* __restrict__ W, const float* __restrict__ bv,
                     const float* xin, int xs, int K, float* yout, int ys) {
        float acc0, acc1;
        const float b = bv[n];
        acc0 = b; acc1 = b;
        #pragma unroll 4
        for (int k = 0; k < K; ++k) {
            const float w = W[k * 256 + n];
            acc0 += xin[(rh * 2 + 0) * xs + k] * w;
            acc1 += xin[(rh * 2 + 1) * xs + k] * w;
        }
        yout[(rh * 2 + 0) * ys + n] = tanhl(acc0);
        yout[(rh * 2 + 1) * ys + n] = tanhl(acc1);
    };

    layer(Wa1, ba1, &xf[0][0], F + 1, 128, &hb[0][0][0], 257);   // actor L1
    __syncthreads();
    layer(Wa2, ba2, &hb[0][0][0], 257, 256, &hb[1][0][0], 257);  // actor L2
    __syncthreads();
    layer(Wc1, bc1, &xf[0][0], F + 1, 128, &hb[0][0][0], 257);   // critic L1
    if (tid < 32) {                                              // actor L3: mean + std
        const int r = tid >> 3, aa = tid & 7;
        float acc = ba3[aa];
        #pragma unroll 4
        for (int k = 0; k < 256; ++k) acc += hb[1][r][k] * Wa3[k * 8 + aa];
        out[(size_t)(r0 + r) * 17 + aa]     = acc;
        out[(size_t)(r0 + r) * 17 + 8 + aa] = __expf(logstd[aa]);
    }
    __syncthreads();
    layer(Wc2, bc2, &hb[0][0][0], 257, 256, &hb[1][0][0], 257);  // critic L2
    __syncthreads();
    if (tid < 4) {                                               // critic L3: value
        const int r = tid;
        float acc = bc3[0];
        #pragma unroll 4
        for (int k = 0; k < 256; ++k) acc += hb[1][r][k] * Wc3[k];
        out[(size_t)(r0 + r) * 17 + 16] = acc;
    }
}

extern "C" void kernel_launch(void* const* d_in, const int* in_sizes, int n_in,
                              void* d_out, int out_size, void* d_ws, size_t ws_size,
                              hipStream_t stream) {
    (void)in_sizes; (void)n_in; (void)d_ws; (void)ws_size; (void)out_size;
    const float* hin = (const float*)d_in[0];
    const float* Wx  = (const float*)d_in[1];
    const float* Wh  = (const float*)d_in[2];
    const float* bh  = (const float*)d_in[3];
    const float* Wa1 = (const float*)d_in[4];
    const float* ba1 = (const float*)d_in[5];
    const float* Wa2 = (const float*)d_in[6];
    const float* ba2 = (const float*)d_in[7];
    const float* Wa3 = (const float*)d_in[8];
    const float* ba3 = (const float*)d_in[9];
    const float* ls  = (const float*)d_in[10];
    const float* Wc1 = (const float*)d_in[11];
    const float* bc1 = (const float*)d_in[12];
    const float* Wc2 = (const float*)d_in[13];
    const float* bc2 = (const float*)d_in[14];
    const float* Wc3 = (const float*)d_in[15];
    const float* bc3 = (const float*)d_in[16];

    hipLaunchKernelGGL(ac_fused, dim3(256), dim3(512), 0, stream,
                       hin, Wx, Wh, bh, Wa1, ba1, Wa2, ba2, Wa3, ba3, ls,
                       Wc1, bc1, Wc2, bc2, Wc3, bc3, (float*)d_out);
}

// Round 4
// 425.587 us; speedup vs baseline: 1.5076x; 1.1831x over previous
//
#include <hip/hip_runtime.h>

// ActorCritic fused kernel R7: LSTM scan (B=1024,T=256,F=128,H=128) + MLP heads.
//
// R6 failed to run; it declared ~84KB static LDS (over the 64KB static limit)
// for an xg buffer that turns out to be unnecessary. R7 keeps R6's key idea
// (hoist the non-recurrent x-projection out of the scan) but routes xg through
// REGISTERS instead of LDS:
//  - phase A-tile row m <-> (batch m>>2, timestep t0+mt*4+(m&3)). MFMA D rows
//    4q+reg then give lane (q,m16) exactly xg[batch q][t0+mt*4+reg][ncol] --
//    the values that lane consumes at steps i = mt*4+reg. accP[2][4] f32x4
//    (32 regs), statically indexed via full unroll. No xg LDS at all.
//  - x-tile (8KB f16, fragment order) staged cooperatively once per 8 steps:
//    2x float4/thread loaded at step 2 of the PREVIOUS group (~3000cy cover),
//    packed + ds_written at step 7 before the existing barrier. Zero extra
//    barriers; zero global ops on the step critical path.
//  - steady step: 4x ds_read_b128 (h frags) + 16 MFMA (C preloaded with xg)
//    + activation + 4x ds_write_b16 + lgkmcnt(0) + s_barrier.
//  - LDS ~26KB; register peak ~230/256 -> no spill expected (check WRITE_SIZE).

typedef _Float16 f16x8 __attribute__((ext_vector_type(8)));
typedef _Float16 f16x4 __attribute__((ext_vector_type(4)));
typedef float    f32x4 __attribute__((ext_vector_type(4)));

#define NLOG2E (-1.4426950408889634f)

__device__ __forceinline__ float rcpf(float x) { return __builtin_amdgcn_rcpf(x); }
__device__ __forceinline__ float ex2(float x)  { return __builtin_amdgcn_exp2f(x); }

__device__ __forceinline__ f16x4 pack4(const float4 a) {
    f16x4 v;
    v[0] = (_Float16)a.x; v[1] = (_Float16)a.y;
    v[2] = (_Float16)a.z; v[3] = (_Float16)a.w;
    return v;
}

__global__ __launch_bounds__(512, 2)
void ac_fused(const float* __restrict__ hin,
              const float* __restrict__ Wx, const float* __restrict__ Wh,
              const float* __restrict__ bh,
              const float* __restrict__ Wa1, const float* __restrict__ ba1,
              const float* __restrict__ Wa2, const float* __restrict__ ba2,
              const float* __restrict__ Wa3, const float* __restrict__ ba3,
              const float* __restrict__ logstd,
              const float* __restrict__ Wc1, const float* __restrict__ bc1,
              const float* __restrict__ Wc2, const float* __restrict__ bc2,
              const float* __restrict__ Wc3, const float* __restrict__ bc3,
              float* __restrict__ out)
{
    constexpr int T = 256, F = 128, H = 128, G = 512; // G = 4*H

    // h-operand staging, MFMA fragment order over K=128 (h dims only):
    // chunk = kt*64 + q*16 + m holds h[batch m>>2][k = kt*32 + q*8 + j].
    __shared__ f16x8 Abuf[2][256];   // 2 x 4 KB, ping-pong
    // x-tile for the current 8-step group, 2 Mtiles in the same chunk layout;
    // Mtile mt row m <-> x[batch m>>2][t0 + mt*4 + (m&3)].
    __shared__ f16x8 Axg[2][256];    // 2 x 4 KB
    __shared__ float xf[4][F + 1];   // final hidden (fp32)
    __shared__ float hb[2][4][257];  // head layer ping-pong

    const int tid  = threadIdx.x;
    const int lane = tid & 63;
    const int wv   = tid >> 6;    // wave 0..7
    const int m16  = lane & 15;
    const int q    = lane >> 4;   // quad 0..3
    const int r0   = blockIdx.x << 2;
    const int ncol = (wv << 4) + m16;   // this wave/lane's output column per gate

    // ---- load weight B-fragments into registers (-> AGPRs) ----
    f16x8 bwx[4][4], bwh[4][4];
    #pragma unroll
    for (int kt = 0; kt < 4; ++kt) {
        #pragma unroll
        for (int s = 0; s < 4; ++s) {
            f16x8 vx, vh;
            #pragma unroll
            for (int j = 0; j < 8; ++j) {
                const int k = (kt << 5) + (q << 3) + j;   // 0..127
                vx[j] = (_Float16)Wx[k * G + s * H + ncol];
                vh[j] = (_Float16)Wh[k * G + s * H + ncol];
            }
            bwx[s][kt] = vx;
            bwh[s][kt] = vh;
        }
    }
    // bias folded into the exp2 argument:  sig(z+b) = rcp(1 + 2^(z*NLOG2E + nb))
    const float nbi = NLOG2E * bh[0 * H + ncol];
    const float nbf = NLOG2E * bh[1 * H + ncol];
    const float nbg = 2.0f * NLOG2E * bh[2 * H + ncol];
    const float nbo = NLOG2E * bh[3 * H + ncol];

    // ---- x staging ids: thread stages chunk xc = tid>>1, half xh = tid&1.
    //      chunk row m = xc&15 -> batch (xc>>2)&3, tsub = xc&3. ----
    const int xc = tid >> 1;
    const int xh = tid & 1;
    const int xk0 = ((xc >> 6) << 5) + (((xc >> 4) & 3) << 3) + (xh << 2);
    const float* pgbase = hin + (size_t)(r0 + ((xc >> 2) & 3)) * T * F
                              + (size_t)(xc & 3) * F + xk0;

    // h-write base: dim ncol -> chunk cb + m, halfword ncol&7;
    // this lane's batch row q occupies m = 4q..4q+3 (consecutive chunks, +8 hw).
    const int hw0 = ((((ncol >> 5) << 6) + (((ncol >> 3) & 3) << 4) + (q << 2)) << 3)
                    + (ncol & 7);

    // ---- zero both h buffers (h_{-1} = 0) ----
    {
        f16x8 zz = {};
        ((f16x8*)Abuf)[tid] = zz;    // 512 chunks = both buffers
    }

    // ---- prologue: load + stage group-0 x-tile ----
    {
        const float4 xp0 = *(const float4*)(pgbase);                    // mt 0
        const float4 xp1 = *(const float4*)(pgbase + 4 * (size_t)F);    // mt 1
        __syncthreads();   // Abuf zeros visible; Axg not yet read by anyone
        *(f16x4*)((_Float16*)&Axg[0][0] + xc * 8 + xh * 4) = pack4(xp0);
        *(f16x4*)((_Float16*)&Axg[1][0] + xc * 8 + xh * 4) = pack4(xp1);
    }
    asm volatile("s_waitcnt lgkmcnt(0)" ::: "memory");
    __builtin_amdgcn_s_barrier();

    float cstate = 0.0f;
    float hcur   = 0.0f;

    for (int t0 = 0; t0 < T; t0 += 8) {
        // ========== PHASE: P[mt][s] = x-tile @ Wx (xg in registers) ==========
        // Lane (q,m16): P[mt][s][reg] = xg[batch q][t0+mt*4+reg][s*H + ncol].
        f32x4 P[2][4];
        #pragma unroll
        for (int mt = 0; mt < 2; ++mt)
            #pragma unroll
            for (int s = 0; s < 4; ++s) P[mt][s] = f32x4{0.f, 0.f, 0.f, 0.f};
        #pragma unroll
        for (int kt = 0; kt < 4; ++kt) {
            const f16x8 fr0 = Axg[0][(kt << 6) + lane];
            const f16x8 fr1 = Axg[1][(kt << 6) + lane];
            P[0][0] = __builtin_amdgcn_mfma_f32_16x16x32_f16(fr0, bwx[0][kt], P[0][0], 0, 0, 0);
            P[0][1] = __builtin_amdgcn_mfma_f32_16x16x32_f16(fr0, bwx[1][kt], P[0][1], 0, 0, 0);
            P[0][2] = __builtin_amdgcn_mfma_f32_16x16x32_f16(fr0, bwx[2][kt], P[0][2], 0, 0, 0);
            P[0][3] = __builtin_amdgcn_mfma_f32_16x16x32_f16(fr0, bwx[3][kt], P[0][3], 0, 0, 0);
            P[1][0] = __builtin_amdgcn_mfma_f32_16x16x32_f16(fr1, bwx[0][kt], P[1][0], 0, 0, 0);
            P[1][1] = __builtin_amdgcn_mfma_f32_16x16x32_f16(fr1, bwx[1][kt], P[1][1], 0, 0, 0);
            P[1][2] = __builtin_amdgcn_mfma_f32_16x16x32_f16(fr1, bwx[2][kt], P[1][2], 0, 0, 0);
            P[1][3] = __builtin_amdgcn_mfma_f32_16x16x32_f16(fr1, bwx[3][kt], P[1][3], 0, 0, 0);
        }

        // ========== 8 steady steps (h recurrence only) ==========
        float4 xp0n, xp1n;
        #pragma unroll
        for (int i = 0; i < 8; ++i) {
            const f16x8* Ac = &Abuf[i & 1][0];          // holds h_{t-1}
            f16x8*       An = &Abuf[(i + 1) & 1][0];    // receives h_t

            // issue next-group x loads early (consumed at i==7; ~5 steps cover)
            if (i == 2) {
                const int t0n = (t0 + 8 < T) ? t0 + 8 : t0;
                xp0n = *(const float4*)(pgbase + (size_t)t0n * F);
                xp1n = *(const float4*)(pgbase + (size_t)(t0n + 4) * F);
            }

            const f16x8 af0 = Ac[lane];
            const f16x8 af1 = Ac[64 + lane];
            const f16x8 af2 = Ac[128 + lane];
            const f16x8 af3 = Ac[192 + lane];

            // C preloaded with this step's xg (all 4 D-rows are the same
            // (batch q, col) output under replication -> broadcast is exact).
            const int mt = i >> 2, rg = i & 3;   // static after unroll
            const float x0 = P[mt][0][rg], x1 = P[mt][1][rg];
            const float x2 = P[mt][2][rg], x3 = P[mt][3][rg];
            f32x4 a0 = {x0, x0, x0, x0}, a1 = {x1, x1, x1, x1};
            f32x4 a2 = {x2, x2, x2, x2}, a3 = {x3, x3, x3, x3};

            a0 = __builtin_amdgcn_mfma_f32_16x16x32_f16(af0, bwh[0][0], a0, 0, 0, 0);
            a1 = __builtin_amdgcn_mfma_f32_16x16x32_f16(af0, bwh[1][0], a1, 0, 0, 0);
            a2 = __builtin_amdgcn_mfma_f32_16x16x32_f16(af0, bwh[2][0], a2, 0, 0, 0);
            a3 = __builtin_amdgcn_mfma_f32_16x16x32_f16(af0, bwh[3][0], a3, 0, 0, 0);
            a0 = __builtin_amdgcn_mfma_f32_16x16x32_f16(af1, bwh[0][1], a0, 0, 0, 0);
            a1 = __builtin_amdgcn_mfma_f32_16x16x32_f16(af1, bwh[1][1], a1, 0, 0, 0);
            a2 = __builtin_amdgcn_mfma_f32_16x16x32_f16(af1, bwh[2][1], a2, 0, 0, 0);
            a3 = __builtin_amdgcn_mfma_f32_16x16x32_f16(af1, bwh[3][1], a3, 0, 0, 0);
            a0 = __builtin_amdgcn_mfma_f32_16x16x32_f16(af2, bwh[0][2], a0, 0, 0, 0);
            a1 = __builtin_amdgcn_mfma_f32_16x16x32_f16(af2, bwh[1][2], a1, 0, 0, 0);
            a2 = __builtin_amdgcn_mfma_f32_16x16x32_f16(af2, bwh[2][2], a2, 0, 0, 0);
            a3 = __builtin_amdgcn_mfma_f32_16x16x32_f16(af2, bwh[3][2], a3, 0, 0, 0);
            a0 = __builtin_amdgcn_mfma_f32_16x16x32_f16(af3, bwh[0][3], a0, 0, 0, 0);
            a1 = __builtin_amdgcn_mfma_f32_16x16x32_f16(af3, bwh[1][3], a1, 0, 0, 0);
            a2 = __builtin_amdgcn_mfma_f32_16x16x32_f16(af3, bwh[2][3], a2, 0, 0, 0);
            a3 = __builtin_amdgcn_mfma_f32_16x16x32_f16(af3, bwh[3][3], a3, 0, 0, 0);

            const float iv = rcpf(1.0f + ex2(fmaf(a0[0], NLOG2E, nbi)));
            const float fv = rcpf(1.0f + ex2(fmaf(a1[0], NLOG2E, nbf)));
            const float gv = 2.0f * rcpf(1.0f + ex2(fmaf(a2[0], 2.0f * NLOG2E, nbg))) - 1.0f;
            const float ov = rcpf(1.0f + ex2(fmaf(a3[0], NLOG2E, nbo)));
            cstate = fv * cstate + iv * gv;
            const float th = 2.0f * rcpf(1.0f + ex2(cstate * (2.0f * NLOG2E))) - 1.0f;
            hcur = ov * th;

            // h_t -> next buffer, replicated rows m = 4q..4q+3
            {
                const _Float16 hh = (_Float16)hcur;
                _Float16* hp = (_Float16*)An + hw0;
                hp[0]  = hh;
                hp[8]  = hh;
                hp[16] = hh;
                hp[24] = hh;
            }

            // stage next group's x-tile (loads issued at i==2) before barrier
            if (i == 7) {
                *(f16x4*)((_Float16*)&Axg[0][0] + xc * 8 + xh * 4) = pack4(xp0n);
                *(f16x4*)((_Float16*)&Axg[1][0] + xc * 8 + xh * 4) = pack4(xp1n);
            }

            asm volatile("s_waitcnt lgkmcnt(0)" ::: "memory");
            __builtin_amdgcn_s_barrier();
        }
    }

    // ---- final hidden (fp32, pre-rounding) to LDS for the heads ----
    xf[q][ncol] = hcur;
    __syncthreads();

    // ---- MLP heads (fp32 VALU; tiny FLOPs) ----
    const int n  = tid & 255;
    const int rh = tid >> 8;   // 0..1 -> rows {2*rh, 2*rh+1}

    auto tanhl = [&](float x) { return 2.0f * rcpf(1.0f + ex2(x * (2.0f * NLOG2E))) - 1.0f; };

    auto layer = [&](const float* __restrict__ W, const float* __restrict__ bv,
                     const float* xin, int xs, int K, float* yout, int ys) {
        float acc0, acc1;
        const float b = bv[n];
        acc0 = b; acc1 = b;
        #pragma unroll 4
        for (int k = 0; k < K; ++k) {
            const float w = W[k * 256 + n];
            acc0 += xin[(rh * 2 + 0) * xs + k] * w;
            acc1 += xin[(rh * 2 + 1) * xs + k] * w;
        }
        yout[(rh * 2 + 0) * ys + n] = tanhl(acc0);
        yout[(rh * 2 + 1) * ys + n] = tanhl(acc1);
    };

    layer(Wa1, ba1, &xf[0][0], F + 1, 128, &hb[0][0][0], 257);   // actor L1
    __syncthreads();
    layer(Wa2, ba2, &hb[0][0][0], 257, 256, &hb[1][0][0], 257);  // actor L2
    __syncthreads();
    layer(Wc1, bc1, &xf[0][0], F + 1, 128, &hb[0][0][0], 257);   // critic L1
    if (tid < 32) {                                              // actor L3: mean + std
        const int r = tid >> 3, aa = tid & 7;
        float acc = ba3[aa];
        #pragma unroll 4
        for (int k = 0; k < 256; ++k) acc += hb[1][r][k] * Wa3[k * 8 + aa];
        out[(size_t)(r0 + r) * 17 + aa]     = acc;
        out[(size_t)(r0 + r) * 17 + 8 + aa] = __expf(logstd[aa]);
    }
    __syncthreads();
    layer(Wc2, bc2, &hb[0][0][0], 257, 256, &hb[1][0][0], 257);  // critic L2
    __syncthreads();
    if (tid < 4) {                                               // critic L3: value
        const int r = tid;
        float acc = bc3[0];
        #pragma unroll 4
        for (int k = 0; k < 256; ++k) acc += hb[1][r][k] * Wc3[k];
        out[(size_t)(r0 + r) * 17 + 16] = acc;
    }
}

extern "C" void kernel_launch(void* const* d_in, const int* in_sizes, int n_in,
                              void* d_out, int out_size, void* d_ws, size_t ws_size,
                              hipStream_t stream) {
    (void)in_sizes; (void)n_in; (void)d_ws; (void)ws_size; (void)out_size;
    const float* hin = (const float*)d_in[0];
    const float* Wx  = (const float*)d_in[1];
    const float* Wh  = (const float*)d_in[2];
    const float* bh  = (const float*)d_in[3];
    const float* Wa1 = (const float*)d_in[4];
    const float* ba1 = (const float*)d_in[5];
    const float* Wa2 = (const float*)d_in[6];
    const float* ba2 = (const float*)d_in[7];
    const float* Wa3 = (const float*)d_in[8];
    const float* ba3 = (const float*)d_in[9];
    const float* ls  = (const float*)d_in[10];
    const float* Wc1 = (const float*)d_in[11];
    const float* bc1 = (const float*)d_in[12];
    const float* Wc2 = (const float*)d_in[13];
    const float* bc2 = (const float*)d_in[14];
    const float* Wc3 = (const float*)d_in[15];
    const float* bc3 = (const float*)d_in[16];

    hipLaunchKernelGGL(ac_fused, dim3(256), dim3(512), 0, stream,
                       hin, Wx, Wh, bh, Wa1, ba1, Wa2, ba2, Wa3, ba3, ls,
                       Wc1, bc1, Wc2, bc2, Wc3, bc3, (float*)d_out);
}

// Round 6
// 348.928 us; speedup vs baseline: 1.8388x; 1.2197x over previous
//
#include <hip/hip_runtime.h>

// ActorCritic fused kernel R9: LSTM scan (B=1024,T=256,F=128,H=128) + MLP heads.
//
// R8 failed correctness (absmax 0.43): its compact Hbuf[128] assumed the h
// A-fragment is row-independent, but A row m holds h[batch m>>2][k] -- four
// DIFFERENT batch rows; collapsing them raced 4 lanes on one slot.
// R9 keeps the compactness but per batch row: Hbuf holds h[4][128] (1KB vs
// 8KB replicated tile), interleaved as Hbuf[kq][r] (kq = dim>>3, r = batch):
//  - fragment read: Hc[(kt*4+q)*4 + (m16>>2)] -> 16 distinct 16B addrs/wave,
//    2-way bank aliasing (free), 256B served vs R7's 1KB.
//  - h-write: ONE ds_write_b16/lane (vs R7's 4x 8-way-conflicted writes).
//  - A rows 4q..4q+3 are identical (batch q) -> D rows 4q+reg identical ->
//    a[0] select + xg C-broadcast exact, as in R7.
// Heads (from R8, re-audited): unroll 16 k-loops; actor L3 on 256 threads
// (8-seg partials + LDS reduce), critic L3 on 128 threads (32-seg partials).

typedef _Float16 f16x8 __attribute__((ext_vector_type(8)));
typedef _Float16 f16x4 __attribute__((ext_vector_type(4)));
typedef float    f32x4 __attribute__((ext_vector_type(4)));

#define NLOG2E (-1.4426950408889634f)

__device__ __forceinline__ float rcpf(float x) { return __builtin_amdgcn_rcpf(x); }
__device__ __forceinline__ float ex2(float x)  { return __builtin_amdgcn_exp2f(x); }

__device__ __forceinline__ f16x4 pack4(const float4 a) {
    f16x4 v;
    v[0] = (_Float16)a.x; v[1] = (_Float16)a.y;
    v[2] = (_Float16)a.z; v[3] = (_Float16)a.w;
    return v;
}

__global__ __launch_bounds__(512, 2)
void ac_fused(const float* __restrict__ hin,
              const float* __restrict__ Wx, const float* __restrict__ Wh,
              const float* __restrict__ bh,
              const float* __restrict__ Wa1, const float* __restrict__ ba1,
              const float* __restrict__ Wa2, const float* __restrict__ ba2,
              const float* __restrict__ Wa3, const float* __restrict__ ba3,
              const float* __restrict__ logstd,
              const float* __restrict__ Wc1, const float* __restrict__ bc1,
              const float* __restrict__ Wc2, const float* __restrict__ bc2,
              const float* __restrict__ Wc3, const float* __restrict__ bc3,
              float* __restrict__ out)
{
    constexpr int T = 256, F = 128, H = 128, G = 512; // G = 4*H

    // Compact per-row h buffers, interleaved: Hbuf[buf][kq][r] is the f16x8
    // chunk h[batch r][kq*8 .. kq*8+7]. Fragment for lane (q,m16) at kt:
    // Hbuf[buf][kt*4+q][m16>>2]  (A[m16][k=kt*32+q*8+j] = h[m16>>2][k]).
    __shared__ f16x8 Hbuf[2][16][4];   // 2 x 1 KB
    // x-tile for the current 8-step group, fragment order; Mtile mt row m <->
    // x[batch m>>2][t0 + mt*4 + (m&3)].
    __shared__ f16x8 Axg[2][256];      // 2 x 4 KB
    __shared__ float xf[4][F + 1];     // final hidden (fp32)
    __shared__ float hb[2][4][257];    // head layer ping-pong
    __shared__ float redA[4][8][8];    // actor L3 partials
    __shared__ float redC[4][32];      // critic L3 partials

    const int tid  = threadIdx.x;
    const int lane = tid & 63;
    const int wv   = tid >> 6;    // wave 0..7
    const int m16  = lane & 15;
    const int q    = lane >> 4;   // quad 0..3
    const int r0   = blockIdx.x << 2;
    const int ncol = (wv << 4) + m16;   // this wave/lane's output column per gate

    // ---- load weight B-fragments into registers (-> AGPRs) ----
    f16x8 bwx[4][4], bwh[4][4];
    #pragma unroll
    for (int kt = 0; kt < 4; ++kt) {
        #pragma unroll
        for (int s = 0; s < 4; ++s) {
            f16x8 vx, vh;
            #pragma unroll
            for (int j = 0; j < 8; ++j) {
                const int k = (kt << 5) + (q << 3) + j;   // 0..127
                vx[j] = (_Float16)Wx[k * G + s * H + ncol];
                vh[j] = (_Float16)Wh[k * G + s * H + ncol];
            }
            bwx[s][kt] = vx;
            bwh[s][kt] = vh;
        }
    }
    // bias folded into the exp2 argument:  sig(z+b) = rcp(1 + 2^(z*NLOG2E + nb))
    const float nbi = NLOG2E * bh[0 * H + ncol];
    const float nbf = NLOG2E * bh[1 * H + ncol];
    const float nbg = 2.0f * NLOG2E * bh[2 * H + ncol];
    const float nbo = NLOG2E * bh[3 * H + ncol];

    // ---- x staging ids: thread stages chunk xc = tid>>1, half xh = tid&1.
    //      chunk row m = xc&15 -> batch (xc>>2)&3, tsub = xc&3. ----
    const int xc = tid >> 1;
    const int xh = tid & 1;
    const int xk0 = ((xc >> 6) << 5) + (((xc >> 4) & 3) << 3) + (xh << 2);
    const float* pgbase = hin + (size_t)(r0 + ((xc >> 2) & 3)) * T * F
                              + (size_t)(xc & 3) * F + xk0;

    // h fragment-read base index (chunk units within one buffer):
    // index = kt*16 + (q*4 + (m16>>2))
    const int hr0 = (q << 2) + (m16 >> 2);
    // h-write halfword index within one buffer: chunk kq=ncol>>3, row q, j=ncol&7
    const int hw  = ((((ncol >> 3) << 2) + q) << 3) + (ncol & 7);

    // ---- zero h buffers (h_{-1} = 0) ----
    if (tid < 128) {
        f16x8 zz = {};
        ((f16x8*)Hbuf)[tid] = zz;
    }

    // ---- prologue: load + stage group-0 x-tile ----
    {
        const float4 xp0 = *(const float4*)(pgbase);                    // mt 0
        const float4 xp1 = *(const float4*)(pgbase + 4 * (size_t)F);    // mt 1
        __syncthreads();   // Hbuf zeros visible; Axg not yet read by anyone
        *(f16x4*)((_Float16*)&Axg[0][0] + xc * 8 + xh * 4) = pack4(xp0);
        *(f16x4*)((_Float16*)&Axg[1][0] + xc * 8 + xh * 4) = pack4(xp1);
    }
    asm volatile("s_waitcnt lgkmcnt(0)" ::: "memory");
    __builtin_amdgcn_s_barrier();

    float cstate = 0.0f;
    float hcur   = 0.0f;

    for (int t0 = 0; t0 < T; t0 += 8) {
        // ========== PHASE: P[mt][s] = x-tile @ Wx (xg in registers) ==========
        // Lane (q,m16): P[mt][s][reg] = xg[batch q][t0+mt*4+reg][s*H + ncol].
        f32x4 P[2][4];
        #pragma unroll
        for (int mt = 0; mt < 2; ++mt)
            #pragma unroll
            for (int s = 0; s < 4; ++s) P[mt][s] = f32x4{0.f, 0.f, 0.f, 0.f};
        #pragma unroll
        for (int kt = 0; kt < 4; ++kt) {
            const f16x8 fr0 = Axg[0][(kt << 6) + lane];
            const f16x8 fr1 = Axg[1][(kt << 6) + lane];
            P[0][0] = __builtin_amdgcn_mfma_f32_16x16x32_f16(fr0, bwx[0][kt], P[0][0], 0, 0, 0);
            P[0][1] = __builtin_amdgcn_mfma_f32_16x16x32_f16(fr0, bwx[1][kt], P[0][1], 0, 0, 0);
            P[0][2] = __builtin_amdgcn_mfma_f32_16x16x32_f16(fr0, bwx[2][kt], P[0][2], 0, 0, 0);
            P[0][3] = __builtin_amdgcn_mfma_f32_16x16x32_f16(fr0, bwx[3][kt], P[0][3], 0, 0, 0);
            P[1][0] = __builtin_amdgcn_mfma_f32_16x16x32_f16(fr1, bwx[0][kt], P[1][0], 0, 0, 0);
            P[1][1] = __builtin_amdgcn_mfma_f32_16x16x32_f16(fr1, bwx[1][kt], P[1][1], 0, 0, 0);
            P[1][2] = __builtin_amdgcn_mfma_f32_16x16x32_f16(fr1, bwx[2][kt], P[1][2], 0, 0, 0);
            P[1][3] = __builtin_amdgcn_mfma_f32_16x16x32_f16(fr1, bwx[3][kt], P[1][3], 0, 0, 0);
        }

        // ========== 8 steady steps (h recurrence only) ==========
        float4 xp0n, xp1n;
        #pragma unroll
        for (int i = 0; i < 8; ++i) {
            const int t = t0 + i;
            const f16x8* Hc = &Hbuf[t & 1][0][0];          // holds h_{t-1}
            _Float16*    Hn = (_Float16*)&Hbuf[(t + 1) & 1][0][0];

            // issue next-group x loads early (consumed at i==7; ~5 steps cover)
            if (i == 2) {
                const int t0n = (t0 + 8 < T) ? t0 + 8 : t0;
                xp0n = *(const float4*)(pgbase + (size_t)t0n * F);
                xp1n = *(const float4*)(pgbase + (size_t)(t0n + 4) * F);
            }

            // A-fragments: per-row compact reads (16 distinct 16B addrs/wave,
            // 2-way bank aliasing = free)
            const f16x8 af0 = Hc[hr0];
            const f16x8 af1 = Hc[16 + hr0];
            const f16x8 af2 = Hc[32 + hr0];
            const f16x8 af3 = Hc[48 + hr0];

            // C preloaded with this step's xg (A rows 4q..4q+3 identical ->
            // D rows 4q+reg identical -> broadcast exact).
            const int mt = i >> 2, rg = i & 3;   // static after unroll
            const float x0 = P[mt][0][rg], x1 = P[mt][1][rg];
            const float x2 = P[mt][2][rg], x3 = P[mt][3][rg];
            f32x4 a0 = {x0, x0, x0, x0}, a1 = {x1, x1, x1, x1};
            f32x4 a2 = {x2, x2, x2, x2}, a3 = {x3, x3, x3, x3};

            a0 = __builtin_amdgcn_mfma_f32_16x16x32_f16(af0, bwh[0][0], a0, 0, 0, 0);
            a1 = __builtin_amdgcn_mfma_f32_16x16x32_f16(af0, bwh[1][0], a1, 0, 0, 0);
            a2 = __builtin_amdgcn_mfma_f32_16x16x32_f16(af0, bwh[2][0], a2, 0, 0, 0);
            a3 = __builtin_amdgcn_mfma_f32_16x16x32_f16(af0, bwh[3][0], a3, 0, 0, 0);
            a0 = __builtin_amdgcn_mfma_f32_16x16x32_f16(af1, bwh[0][1], a0, 0, 0, 0);
            a1 = __builtin_amdgcn_mfma_f32_16x16x32_f16(af1, bwh[1][1], a1, 0, 0, 0);
            a2 = __builtin_amdgcn_mfma_f32_16x16x32_f16(af1, bwh[2][1], a2, 0, 0, 0);
            a3 = __builtin_amdgcn_mfma_f32_16x16x32_f16(af1, bwh[3][1], a3, 0, 0, 0);
            a0 = __builtin_amdgcn_mfma_f32_16x16x32_f16(af2, bwh[0][2], a0, 0, 0, 0);
            a1 = __builtin_amdgcn_mfma_f32_16x16x32_f16(af2, bwh[1][2], a1, 0, 0, 0);
            a2 = __builtin_amdgcn_mfma_f32_16x16x32_f16(af2, bwh[2][2], a2, 0, 0, 0);
            a3 = __builtin_amdgcn_mfma_f32_16x16x32_f16(af2, bwh[3][2], a3, 0, 0, 0);
            a0 = __builtin_amdgcn_mfma_f32_16x16x32_f16(af3, bwh[0][3], a0, 0, 0, 0);
            a1 = __builtin_amdgcn_mfma_f32_16x16x32_f16(af3, bwh[1][3], a1, 0, 0, 0);
            a2 = __builtin_amdgcn_mfma_f32_16x16x32_f16(af3, bwh[2][3], a2, 0, 0, 0);
            a3 = __builtin_amdgcn_mfma_f32_16x16x32_f16(af3, bwh[3][3], a3, 0, 0, 0);

            const float iv = rcpf(1.0f + ex2(fmaf(a0[0], NLOG2E, nbi)));
            const float fv = rcpf(1.0f + ex2(fmaf(a1[0], NLOG2E, nbf)));
            const float gv = 2.0f * rcpf(1.0f + ex2(fmaf(a2[0], 2.0f * NLOG2E, nbg))) - 1.0f;
            const float ov = rcpf(1.0f + ex2(fmaf(a3[0], NLOG2E, nbo)));
            cstate = fv * cstate + iv * gv;
            const float th = 2.0f * rcpf(1.0f + ex2(cstate * (2.0f * NLOG2E))) - 1.0f;
            hcur = ov * th;

            // h_t -> compact next buffer: ONE b16 write per lane
            Hn[hw] = (_Float16)hcur;

            // stage next group's x-tile (loads issued at i==2) before barrier
            if (i == 7) {
                *(f16x4*)((_Float16*)&Axg[0][0] + xc * 8 + xh * 4) = pack4(xp0n);
                *(f16x4*)((_Float16*)&Axg[1][0] + xc * 8 + xh * 4) = pack4(xp1n);
            }

            asm volatile("s_waitcnt lgkmcnt(0)" ::: "memory");
            __builtin_amdgcn_s_barrier();
        }
    }

    // ---- final hidden (fp32, pre-rounding) to LDS for the heads ----
    xf[q][ncol] = hcur;
    __syncthreads();

    // ---- MLP heads (fp32 VALU; tiny FLOPs) ----
    const int n  = tid & 255;
    const int rh = tid >> 8;   // 0..1 -> rows {2*rh, 2*rh+1}

    auto tanhl = [&](float x) { return 2.0f * rcpf(1.0f + ex2(x * (2.0f * NLOG2E))) - 1.0f; };

    auto layer = [&](const float* __restrict__ W, const float* __restrict__ bv,
                     const float* xin, int xs, int K, float* yout, int ys) {
        float acc0, acc1;
        const float b = bv[n];
        acc0 = b; acc1 = b;
        #pragma unroll 16
        for (int k = 0; k < K; ++k) {
            const float w = W[k * 256 + n];
            acc0 += xin[(rh * 2 + 0) * xs + k] * w;
            acc1 += xin[(rh * 2 + 1) * xs + k] * w;
        }
        yout[(rh * 2 + 0) * ys + n] = tanhl(acc0);
        yout[(rh * 2 + 1) * ys + n] = tanhl(acc1);
    };

    layer(Wa1, ba1, &xf[0][0], F + 1, 128, &hb[0][0][0], 257);   // actor L1
    __syncthreads();
    layer(Wa2, ba2, &hb[0][0][0], 257, 256, &hb[1][0][0], 257);  // actor L2
    __syncthreads();
    layer(Wc1, bc1, &xf[0][0], F + 1, 128, &hb[0][0][0], 257);   // critic L1
    // actor L3 partials on 256 threads: (r, aa, seg) x K-chunk of 32
    if (tid < 256) {
        const int r = tid >> 6, aa = (tid >> 3) & 7, seg = tid & 7;
        float acc = 0.0f;
        const int k0 = seg << 5;
        #pragma unroll 16
        for (int k = k0; k < k0 + 32; ++k) acc += hb[1][r][k] * Wa3[k * 8 + aa];
        redA[r][aa][seg] = acc;
    }
    __syncthreads();
    layer(Wc2, bc2, &hb[0][0][0], 257, 256, &hb[1][0][0], 257);  // critic L2
    if (tid < 32) {                                              // actor L3 reduce
        const int r = tid >> 3, aa = tid & 7;
        float acc = ba3[aa];
        #pragma unroll
        for (int s = 0; s < 8; ++s) acc += redA[r][aa][s];
        out[(size_t)(r0 + r) * 17 + aa]     = acc;
        out[(size_t)(r0 + r) * 17 + 8 + aa] = __expf(logstd[aa]);
    }
    __syncthreads();
    // critic L3 partials on 128 threads: (r, seg) x K-chunk of 8
    if (tid < 128) {
        const int r = tid >> 5, seg = tid & 31;
        float acc = 0.0f;
        const int k0 = seg << 3;
        #pragma unroll
        for (int k = k0; k < k0 + 8; ++k) acc += hb[1][r][k] * Wc3[k];
        redC[r][seg] = acc;
    }
    __syncthreads();
    if (tid < 4) {                                               // critic L3 reduce
        float acc = bc3[0];
        #pragma unroll
        for (int s = 0; s < 32; ++s) acc += redC[tid][s];
        out[(size_t)(r0 + tid) * 17 + 16] = acc;
    }
}

extern "C" void kernel_launch(void* const* d_in, const int* in_sizes, int n_in,
                              void* d_out, int out_size, void* d_ws, size_t ws_size,
                              hipStream_t stream) {
    (void)in_sizes; (void)n_in; (void)d_ws; (void)ws_size; (void)out_size;
    const float* hin = (const float*)d_in[0];
    const float* Wx  = (const float*)d_in[1];
    const float* Wh  = (const float*)d_in[2];
    const float* bh  = (const float*)d_in[3];
    const float* Wa1 = (const float*)d_in[4];
    const float* ba1 = (const float*)d_in[5];
    const float* Wa2 = (const float*)d_in[6];
    const float* ba2 = (const float*)d_in[7];
    const float* Wa3 = (const float*)d_in[8];
    const float* ba3 = (const float*)d_in[9];
    const float* ls  = (const float*)d_in[10];
    const float* Wc1 = (const float*)d_in[11];
    const float* bc1 = (const float*)d_in[12];
    const float* Wc2 = (const float*)d_in[13];
    const float* bc2 = (const float*)d_in[14];
    const float* Wc3 = (const float*)d_in[15];
    const float* bc3 = (const float*)d_in[16];

    hipLaunchKernelGGL(ac_fused, dim3(256), dim3(512), 0, stream,
                       hin, Wx, Wh, bh, Wa1, ba1, Wa2, ba2, Wa3, ba3, ls,
                       Wc1, bc1, Wc2, bc2, Wc3, bc3, (float*)d_out);
}

// Round 7
// 342.196 us; speedup vs baseline: 1.8750x; 1.0197x over previous
//
#include <hip/hip_runtime.h>

// ActorCritic fused kernel R10: LSTM scan (B=1024,T=256,F=128,H=128) + MLP heads.
//
// R9 post-mortem: 205us steady; conflicts fixed (4.2M->523K); VGPR 128 + 128
// AGPR weights = exactly the 256-reg cap (2 waves/SIMD) -> no headroom, light
// spill (WRITE 6.7MB). Step ~1730cy vs ~500cy chain model: issue-bound VALU
// (acc-init broadcasts, xg adds, transcendentals, addressing) + exposed
// latency. R10 = instruction diet, zero added registers:
//  - persistent zero quad zq as MFMA C-operand: a = mfma(af,bw,zq) removes
//    16 v_mov/step/wave AND the init->MFMA dependency (first MFMA issues as
//    soon as af0 lands). Phase: same trick (-32 movs/phase).
//  - xg folded into activation: at phase end P <- P*c_s + nb_s (c=NLOG2E;
//    2*NLOG2E for g-gate), step does ex2(fmaf(a[0], c_s, Pn)) -- the 4
//    per-step adds vanish into 32 batched fmas/phase.
//  - heads: actor (tid<256) and critic (tid>=256) L1/L2 run CONCURRENTLY
//    (wave-uniform W pointer select, 4 rows/thread); one fewer barrier.

typedef _Float16 f16x8 __attribute__((ext_vector_type(8)));
typedef _Float16 f16x4 __attribute__((ext_vector_type(4)));
typedef float    f32x4 __attribute__((ext_vector_type(4)));

#define NLOG2E (-1.4426950408889634f)

__device__ __forceinline__ float rcpf(float x) { return __builtin_amdgcn_rcpf(x); }
__device__ __forceinline__ float ex2(float x)  { return __builtin_amdgcn_exp2f(x); }

__device__ __forceinline__ f16x4 pack4(const float4 a) {
    f16x4 v;
    v[0] = (_Float16)a.x; v[1] = (_Float16)a.y;
    v[2] = (_Float16)a.z; v[3] = (_Float16)a.w;
    return v;
}

__global__ __launch_bounds__(512, 2)
void ac_fused(const float* __restrict__ hin,
              const float* __restrict__ Wx, const float* __restrict__ Wh,
              const float* __restrict__ bh,
              const float* __restrict__ Wa1, const float* __restrict__ ba1,
              const float* __restrict__ Wa2, const float* __restrict__ ba2,
              const float* __restrict__ Wa3, const float* __restrict__ ba3,
              const float* __restrict__ logstd,
              const float* __restrict__ Wc1, const float* __restrict__ bc1,
              const float* __restrict__ Wc2, const float* __restrict__ bc2,
              const float* __restrict__ Wc3, const float* __restrict__ bc3,
              float* __restrict__ out)
{
    constexpr int T = 256, F = 128, H = 128, G = 512; // G = 4*H

    // Compact per-row h buffers, interleaved: Hbuf[buf][kq][r] is the f16x8
    // chunk h[batch r][kq*8 .. kq*8+7]. Fragment for lane (q,m16) at kt:
    // Hbuf[buf][kt*4+q][m16>>2].
    __shared__ f16x8 Hbuf[2][16][4];    // 2 x 1 KB
    // x-tile, fragment order; Mtile mt row m <-> x[batch m>>2][t0+mt*4+(m&3)].
    __shared__ f16x8 Axg[2][256];       // 2 x 4 KB
    __shared__ float xf[4][F + 1];      // final hidden (fp32)
    __shared__ float hb1[2][4][257];    // L1 out: [actor/critic][row][n]
    __shared__ float hb2[2][4][257];    // L2 out
    __shared__ float redA[4][8][8];     // actor L3 partials
    __shared__ float redC[4][32];       // critic L3 partials

    const int tid  = threadIdx.x;
    const int lane = tid & 63;
    const int wv   = tid >> 6;    // wave 0..7
    const int m16  = lane & 15;
    const int q    = lane >> 4;   // quad 0..3
    const int r0   = blockIdx.x << 2;
    const int ncol = (wv << 4) + m16;   // this wave/lane's output column per gate

    // ---- load weight B-fragments into registers (-> AGPRs) ----
    f16x8 bwx[4][4], bwh[4][4];
    #pragma unroll
    for (int kt = 0; kt < 4; ++kt) {
        #pragma unroll
        for (int s = 0; s < 4; ++s) {
            f16x8 vx, vh;
            #pragma unroll
            for (int j = 0; j < 8; ++j) {
                const int k = (kt << 5) + (q << 3) + j;   // 0..127
                vx[j] = (_Float16)Wx[k * G + s * H + ncol];
                vh[j] = (_Float16)Wh[k * G + s * H + ncol];
            }
            bwx[s][kt] = vx;
            bwh[s][kt] = vh;
        }
    }
    // bias terms for the folded activation: sig(z+b) = rcp(1 + 2^(z*NLOG2E + nb))
    const float nbi = NLOG2E * bh[0 * H + ncol];
    const float nbf = NLOG2E * bh[1 * H + ncol];
    const float nbg = 2.0f * NLOG2E * bh[2 * H + ncol];
    const float nbo = NLOG2E * bh[3 * H + ncol];

    const f32x4 zq = {0.f, 0.f, 0.f, 0.f};   // persistent MFMA zero-C quad

    // ---- x staging ids: thread stages chunk xc = tid>>1, half xh = tid&1.
    //      chunk row m = xc&15 -> batch (xc>>2)&3, tsub = xc&3. ----
    const int xc = tid >> 1;
    const int xh = tid & 1;
    const int xk0 = ((xc >> 6) << 5) + (((xc >> 4) & 3) << 3) + (xh << 2);
    const float* pgbase = hin + (size_t)(r0 + ((xc >> 2) & 3)) * T * F
                              + (size_t)(xc & 3) * F + xk0;

    // h fragment-read base (chunk units): index = kt*16 + (q*4 + (m16>>2))
    const int hr0 = (q << 2) + (m16 >> 2);
    // h-write halfword index: chunk kq=ncol>>3, row q, j=ncol&7
    const int hw  = ((((ncol >> 3) << 2) + q) << 3) + (ncol & 7);

    // ---- zero h buffers (h_{-1} = 0) ----
    if (tid < 128) {
        f16x8 zz = {};
        ((f16x8*)Hbuf)[tid] = zz;
    }

    // ---- prologue: load + stage group-0 x-tile ----
    {
        const float4 xp0 = *(const float4*)(pgbase);                    // mt 0
        const float4 xp1 = *(const float4*)(pgbase + 4 * (size_t)F);    // mt 1
        __syncthreads();   // Hbuf zeros visible; Axg not yet read by anyone
        *(f16x4*)((_Float16*)&Axg[0][0] + xc * 8 + xh * 4) = pack4(xp0);
        *(f16x4*)((_Float16*)&Axg[1][0] + xc * 8 + xh * 4) = pack4(xp1);
    }
    asm volatile("s_waitcnt lgkmcnt(0)" ::: "memory");
    __builtin_amdgcn_s_barrier();

    float cstate = 0.0f;
    float hcur   = 0.0f;

    for (int t0 = 0; t0 < T; t0 += 8) {
        // ========== PHASE: P[mt][s] = x-tile @ Wx, then fold bias+scale ==========
        // Lane (q,m16): P[mt][s][reg] = xg[batch q][t0+mt*4+reg][s*H+ncol].
        f32x4 P[2][4];
        {
            const f16x8 fr0 = Axg[0][lane];
            const f16x8 fr1 = Axg[1][lane];
            P[0][0] = __builtin_amdgcn_mfma_f32_16x16x32_f16(fr0, bwx[0][0], zq, 0, 0, 0);
            P[0][1] = __builtin_amdgcn_mfma_f32_16x16x32_f16(fr0, bwx[1][0], zq, 0, 0, 0);
            P[0][2] = __builtin_amdgcn_mfma_f32_16x16x32_f16(fr0, bwx[2][0], zq, 0, 0, 0);
            P[0][3] = __builtin_amdgcn_mfma_f32_16x16x32_f16(fr0, bwx[3][0], zq, 0, 0, 0);
            P[1][0] = __builtin_amdgcn_mfma_f32_16x16x32_f16(fr1, bwx[0][0], zq, 0, 0, 0);
            P[1][1] = __builtin_amdgcn_mfma_f32_16x16x32_f16(fr1, bwx[1][0], zq, 0, 0, 0);
            P[1][2] = __builtin_amdgcn_mfma_f32_16x16x32_f16(fr1, bwx[2][0], zq, 0, 0, 0);
            P[1][3] = __builtin_amdgcn_mfma_f32_16x16x32_f16(fr1, bwx[3][0], zq, 0, 0, 0);
        }
        #pragma unroll
        for (int kt = 1; kt < 4; ++kt) {
            const f16x8 fr0 = Axg[0][(kt << 6) + lane];
            const f16x8 fr1 = Axg[1][(kt << 6) + lane];
            P[0][0] = __builtin_amdgcn_mfma_f32_16x16x32_f16(fr0, bwx[0][kt], P[0][0], 0, 0, 0);
            P[0][1] = __builtin_amdgcn_mfma_f32_16x16x32_f16(fr0, bwx[1][kt], P[0][1], 0, 0, 0);
            P[0][2] = __builtin_amdgcn_mfma_f32_16x16x32_f16(fr0, bwx[2][kt], P[0][2], 0, 0, 0);
            P[0][3] = __builtin_amdgcn_mfma_f32_16x16x32_f16(fr0, bwx[3][kt], P[0][3], 0, 0, 0);
            P[1][0] = __builtin_amdgcn_mfma_f32_16x16x32_f16(fr1, bwx[0][kt], P[1][0], 0, 0, 0);
            P[1][1] = __builtin_amdgcn_mfma_f32_16x16x32_f16(fr1, bwx[1][kt], P[1][1], 0, 0, 0);
            P[1][2] = __builtin_amdgcn_mfma_f32_16x16x32_f16(fr1, bwx[2][kt], P[1][2], 0, 0, 0);
            P[1][3] = __builtin_amdgcn_mfma_f32_16x16x32_f16(fr1, bwx[3][kt], P[1][3], 0, 0, 0);
        }
        // fold scale+bias: Pn = P*c_s + nb_s  (step then does ex2(a*c_s + Pn))
        #pragma unroll
        for (int mt = 0; mt < 2; ++mt) {
            #pragma unroll
            for (int g = 0; g < 4; ++g) {
                P[mt][0][g] = fmaf(P[mt][0][g], NLOG2E,        nbi);
                P[mt][1][g] = fmaf(P[mt][1][g], NLOG2E,        nbf);
                P[mt][2][g] = fmaf(P[mt][2][g], 2.0f * NLOG2E, nbg);
                P[mt][3][g] = fmaf(P[mt][3][g], NLOG2E,        nbo);
            }
        }

        // ========== 8 steady steps (h recurrence only) ==========
        float4 xp0n, xp1n;
        #pragma unroll
        for (int i = 0; i < 8; ++i) {
            const int t = t0 + i;
            const f16x8* Hc = &Hbuf[t & 1][0][0];          // holds h_{t-1}
            _Float16*    Hn = (_Float16*)&Hbuf[(t + 1) & 1][0][0];

            // A-fragments first (chain head): per-row compact reads
            const f16x8 af0 = Hc[hr0];
            const f16x8 af1 = Hc[16 + hr0];
            const f16x8 af2 = Hc[32 + hr0];
            const f16x8 af3 = Hc[48 + hr0];

            // issue next-group x loads early (consumed at i==7)
            if (i == 2) {
                const int t0n = (t0 + 8 < T) ? t0 + 8 : t0;
                xp0n = *(const float4*)(pgbase + (size_t)t0n * F);
                xp1n = *(const float4*)(pgbase + (size_t)(t0n + 4) * F);
            }

            // zero-C chains: first MFMA uses zq (no init movs, no init dep)
            f32x4 a0 = __builtin_amdgcn_mfma_f32_16x16x32_f16(af0, bwh[0][0], zq, 0, 0, 0);
            f32x4 a1 = __builtin_amdgcn_mfma_f32_16x16x32_f16(af0, bwh[1][0], zq, 0, 0, 0);
            f32x4 a2 = __builtin_amdgcn_mfma_f32_16x16x32_f16(af0, bwh[2][0], zq, 0, 0, 0);
            f32x4 a3 = __builtin_amdgcn_mfma_f32_16x16x32_f16(af0, bwh[3][0], zq, 0, 0, 0);
            a0 = __builtin_amdgcn_mfma_f32_16x16x32_f16(af1, bwh[0][1], a0, 0, 0, 0);
            a1 = __builtin_amdgcn_mfma_f32_16x16x32_f16(af1, bwh[1][1], a1, 0, 0, 0);
            a2 = __builtin_amdgcn_mfma_f32_16x16x32_f16(af1, bwh[2][1], a2, 0, 0, 0);
            a3 = __builtin_amdgcn_mfma_f32_16x16x32_f16(af1, bwh[3][1], a3, 0, 0, 0);
            a0 = __builtin_amdgcn_mfma_f32_16x16x32_f16(af2, bwh[0][2], a0, 0, 0, 0);
            a1 = __builtin_amdgcn_mfma_f32_16x16x32_f16(af2, bwh[1][2], a1, 0, 0, 0);
            a2 = __builtin_amdgcn_mfma_f32_16x16x32_f16(af2, bwh[2][2], a2, 0, 0, 0);
            a3 = __builtin_amdgcn_mfma_f32_16x16x32_f16(af2, bwh[3][2], a3, 0, 0, 0);
            a0 = __builtin_amdgcn_mfma_f32_16x16x32_f16(af3, bwh[0][3], a0, 0, 0, 0);
            a1 = __builtin_amdgcn_mfma_f32_16x16x32_f16(af3, bwh[1][3], a1, 0, 0, 0);
            a2 = __builtin_amdgcn_mfma_f32_16x16x32_f16(af3, bwh[2][3], a2, 0, 0, 0);
            a3 = __builtin_amdgcn_mfma_f32_16x16x32_f16(af3, bwh[3][3], a3, 0, 0, 0);

            // activation with pre-folded xg+bias (Pn): arg = a[0]*c_s + Pn
            const int mt = i >> 2, rg = i & 3;   // static after unroll
            const float iv = rcpf(1.0f + ex2(fmaf(a0[0], NLOG2E,        P[mt][0][rg])));
            const float fv = rcpf(1.0f + ex2(fmaf(a1[0], NLOG2E,        P[mt][1][rg])));
            const float gv = 2.0f * rcpf(1.0f + ex2(fmaf(a2[0], 2.0f * NLOG2E, P[mt][2][rg]))) - 1.0f;
            const float ov = rcpf(1.0f + ex2(fmaf(a3[0], NLOG2E,        P[mt][3][rg])));
            cstate = fv * cstate + iv * gv;
            const float th = 2.0f * rcpf(1.0f + ex2(cstate * (2.0f * NLOG2E))) - 1.0f;
            hcur = ov * th;

            // h_t -> compact next buffer: ONE b16 write per lane
            Hn[hw] = (_Float16)hcur;

            // stage next group's x-tile (loads issued at i==2) before barrier
            if (i == 7) {
                *(f16x4*)((_Float16*)&Axg[0][0] + xc * 8 + xh * 4) = pack4(xp0n);
                *(f16x4*)((_Float16*)&Axg[1][0] + xc * 8 + xh * 4) = pack4(xp1n);
            }

            asm volatile("s_waitcnt lgkmcnt(0)" ::: "memory");
            __builtin_amdgcn_s_barrier();
        }
    }

    // ---- final hidden (fp32, pre-rounding) to LDS for the heads ----
    xf[q][ncol] = hcur;
    __syncthreads();

    // ---- MLP heads: actor (tid<256) and critic (tid>=256) concurrently ----
    const int half = tid >> 8;          // 0 = actor, 1 = critic
    const int n    = tid & 255;
    const float* W1 = half ? Wc1 : Wa1;
    const float* b1 = half ? bc1 : ba1;
    const float* W2 = half ? Wc2 : Wa2;
    const float* b2 = half ? bc2 : ba2;

    auto tanhl = [&](float x) { return 2.0f * rcpf(1.0f + ex2(x * (2.0f * NLOG2E))) - 1.0f; };

    {   // L1: K=128, 4 rows/thread
        float a0, a1, a2, a3;
        const float b = b1[n];
        a0 = a1 = a2 = a3 = b;
        #pragma unroll 16
        for (int k = 0; k < 128; ++k) {
            const float w = W1[k * 256 + n];
            a0 += xf[0][k] * w; a1 += xf[1][k] * w;
            a2 += xf[2][k] * w; a3 += xf[3][k] * w;
        }
        hb1[half][0][n] = tanhl(a0); hb1[half][1][n] = tanhl(a1);
        hb1[half][2][n] = tanhl(a2); hb1[half][3][n] = tanhl(a3);
    }
    __syncthreads();
    {   // L2: K=256, 4 rows/thread
        float a0, a1, a2, a3;
        const float b = b2[n];
        a0 = a1 = a2 = a3 = b;
        #pragma unroll 16
        for (int k = 0; k < 256; ++k) {
            const float w = W2[k * 256 + n];
            a0 += hb1[half][0][k] * w; a1 += hb1[half][1][k] * w;
            a2 += hb1[half][2][k] * w; a3 += hb1[half][3][k] * w;
        }
        hb2[half][0][n] = tanhl(a0); hb2[half][1][n] = tanhl(a1);
        hb2[half][2][n] = tanhl(a2); hb2[half][3][n] = tanhl(a3);
    }
    __syncthreads();
    if (tid < 256) {        // actor L3 partials: (r, aa, seg) x K-chunk of 32
        const int r = tid >> 6, aa = (tid >> 3) & 7, seg = tid & 7;
        float acc = 0.0f;
        const int k0 = seg << 5;
        #pragma unroll 16
        for (int k = k0; k < k0 + 32; ++k) acc += hb2[0][r][k] * Wa3[k * 8 + aa];
        redA[r][aa][seg] = acc;
    } else if (tid < 384) { // critic L3 partials: (r, seg) x K-chunk of 8
        const int u = tid - 256;
        const int r = u >> 5, seg = u & 31;
        float acc = 0.0f;
        const int k0 = seg << 3;
        #pragma unroll
        for (int k = k0; k < k0 + 8; ++k) acc += hb2[1][r][k] * Wc3[k];
        redC[r][seg] = acc;
    }
    __syncthreads();
    if (tid < 32) {                                              // actor out
        const int r = tid >> 3, aa = tid & 7;
        float acc = ba3[aa];
        #pragma unroll
        for (int s = 0; s < 8; ++s) acc += redA[r][aa][s];
        out[(size_t)(r0 + r) * 17 + aa]     = acc;
        out[(size_t)(r0 + r) * 17 + 8 + aa] = __expf(logstd[aa]);
    } else if (tid >= 64 && tid < 68) {                          // critic out
        const int r = tid - 64;
        float acc = bc3[0];
        #pragma unroll
        for (int s = 0; s < 32; ++s) acc += redC[r][s];
        out[(size_t)(r0 + r) * 17 + 16] = acc;
    }
}

extern "C" void kernel_launch(void* const* d_in, const int* in_sizes, int n_in,
                              void* d_out, int out_size, void* d_ws, size_t ws_size,
                              hipStream_t stream) {
    (void)in_sizes; (void)n_in; (void)d_ws; (void)ws_size; (void)out_size;
    const float* hin = (const float*)d_in[0];
    const float* Wx  = (const float*)d_in[1];
    const float* Wh  = (const float*)d_in[2];
    const float* bh  = (const float*)d_in[3];
    const float* Wa1 = (const float*)d_in[4];
    const float* ba1 = (const float*)d_in[5];
    const float* Wa2 = (const float*)d_in[6];
    const float* ba2 = (const float*)d_in[7];
    const float* Wa3 = (const float*)d_in[8];
    const float* ba3 = (const float*)d_in[9];
    const float* ls  = (const float*)d_in[10];
    const float* Wc1 = (const float*)d_in[11];
    const float* bc1 = (const float*)d_in[12];
    const float* Wc2 = (const float*)d_in[13];
    const float* bc2 = (const float*)d_in[14];
    const float* Wc3 = (const float*)d_in[15];
    const float* bc3 = (const float*)d_in[16];

    hipLaunchKernelGGL(ac_fused, dim3(256), dim3(512), 0, stream,
                       hin, Wx, Wh, bh, Wa1, ba1, Wa2, ba2, Wa3, ba3, ls,
                       Wc1, bc1, Wc2, bc2, Wc3, bc3, (float*)d_out);
}